// Round 3
// baseline (349.852 us; speedup 1.0000x reference)
//
#include <hip/hip_runtime.h>
#include <math.h>

#define BB 8
#define CATP 3584   // padded cat K (3572 -> 3584, zeros)
#define CAT_REAL 3572

typedef __attribute__((ext_vector_type(8))) short short8;
typedef __attribute__((ext_vector_type(4))) float f32x4;

__device__ inline ushort f2bf(float f) {
  union { float f; unsigned u; } x;
  x.f = f;
  return (ushort)((x.u + 0x7FFFu + ((x.u >> 16) & 1u)) >> 16);
}
__device__ inline float bf2f(unsigned us) {
  union { unsigned u; float f; } x;
  x.u = us << 16;
  return x.f;
}

// ---------------------------------------------------------------------------
// Dense weight fragment convert helper (one 8-K-strip per thread).
// frag layout (shorts): (((ot*Kc+kc)*4+ii)*64 + l4*16+l15)*8
// ---------------------------------------------------------------------------
__device__ inline void wfrag_conv(const float* __restrict__ srcrow,
                                  ushort* __restrict__ dst, int o, int k8,
                                  int Kc, int Kreal) {
  const int k = k8 * 8;
  float v[8];
  if (Kreal > 0) {
#pragma unroll
    for (int q = 0; q < 8; q++) v[q] = (k + q < Kreal) ? srcrow[k + q] : 0.f;
  } else {
    const float4 f0 = *(const float4*)(srcrow + k);
    const float4 f1 = *(const float4*)(srcrow + k + 4);
    v[0] = f0.x; v[1] = f0.y; v[2] = f0.z; v[3] = f0.w;
    v[4] = f1.x; v[5] = f1.y; v[6] = f1.z; v[7] = f1.w;
  }
  uint4 pk;
  pk.x = (unsigned)f2bf(v[0]) | ((unsigned)f2bf(v[1]) << 16);
  pk.y = (unsigned)f2bf(v[2]) | ((unsigned)f2bf(v[3]) << 16);
  pk.z = (unsigned)f2bf(v[4]) | ((unsigned)f2bf(v[5]) << 16);
  pk.w = (unsigned)f2bf(v[6]) | ((unsigned)f2bf(v[7]) << 16);
  const int ot = o >> 6, ii = (o >> 4) & 3, l15 = o & 15;
  const int kc = k8 >> 2, l4 = k8 & 3;
  const size_t flat =
      ((((size_t)ot * Kc + kc) * 4 + ii) * 64 + l4 * 16 + l15) * 8;
  *(uint4*)(dst + flat) = pk;
}

// ---------------------------------------------------------------------------
// Anchor conv weight frags [O][C][K] -> fragment order (no LDS).
// ---------------------------------------------------------------------------
template <int Cin, int Kf>
__device__ void cpT_tile(const float* __restrict__ W, ushort* __restrict__ D,
                         int nt, int cc) {
  const int tid = threadIdx.x;
  const int j = tid >> 6, l4 = (tid >> 4) & 3, l15 = tid & 15;
  const int o = nt * 64 + j * 16 + l15;
  const int cb = cc * 32 + l4 * 8;
  ushort rg[8][Kf];
#pragma unroll
  for (int q = 0; q < 8; q++) {
    const float* row = W + ((size_t)o * Cin + cb + q) * Kf;
#pragma unroll
    for (int kq = 0; kq < Kf / 4; kq++) {
      const float4 f = *(const float4*)(row + kq * 4);
      rg[q][kq * 4 + 0] = f2bf(f.x);
      rg[q][kq * 4 + 1] = f2bf(f.y);
      rg[q][kq * 4 + 2] = f2bf(f.z);
      rg[q][kq * 4 + 3] = f2bf(f.w);
    }
  }
#pragma unroll
  for (int k = 0; k < Kf; k++) {
    uint4 pk;
    pk.x = (unsigned)rg[0][k] | ((unsigned)rg[1][k] << 16);
    pk.y = (unsigned)rg[2][k] | ((unsigned)rg[3][k] << 16);
    pk.z = (unsigned)rg[4][k] | ((unsigned)rg[5][k] << 16);
    pk.w = (unsigned)rg[6][k] | ((unsigned)rg[7][k] << 16);
    *(uint4*)(D + ((size_t)(nt * Kf + k) * (Cin >> 5) + cc) * 2048 + tid * 8) = pk;
  }
}

// ---------------------------------------------------------------------------
// PREP-EARLY: only what launch B needs (Wcomb, Wcp0T, Ft, FfT, lastcls,
// locres). Heavy converts (Wprop/WcpT/Wroi) moved into fused_B tail blocks.
//   [0,384)   Wcomb dense convert
//   [384,512) Wcp0T frag convert
//   [512,904) activation transposes
// ---------------------------------------------------------------------------
__global__ __launch_bounds__(256) void prep_early_kernel(
    const float* __restrict__ w_cur, const float* __restrict__ w_lr,
    ushort* __restrict__ Wcomb, const float* __restrict__ w_cp0,
    ushort* __restrict__ Wcp0T, const float* __restrict__ feature,
    const float* __restrict__ frame_feat, const float* __restrict__ lastcls,
    const float* __restrict__ locres, ushort* __restrict__ Ft,
    ushort* __restrict__ FfT, ushort* __restrict__ cat) {
  __shared__ float tile[64 * 65];
  const int bid = blockIdx.x;
  if (bid < 384) {
    const int i = bid * 256 + threadIdx.x;  // [0, 98304)
    const int o = i >> 6, k8 = i & 63;
    const float* srcrow = (o < 512) ? w_cur + (size_t)o * 512
                                    : w_lr + (size_t)(o - 512) * 512;
    wfrag_conv(srcrow, Wcomb, o, k8, 16, 0);
    return;
  }
  if (bid < 512) {
    const int r = bid - 384;
    cpT_tile<512, 8>(w_cp0, Wcp0T, r >> 4, r & 15);
    return;
  }
  const int local = bid - 512;
  const float* src;
  ushort* dst;
  int Cr, Cw, L, rs, co, cblk, lblk, b;
  if (local < 64) {
    src = feature; dst = Ft; Cr = 512; Cw = 512; L = 64; rs = 512; co = 0;
    cblk = local & 7; lblk = 0; b = local >> 3;
  } else if (local < 320) {
    const int r = local - 64;
    src = frame_feat; dst = FfT; Cr = 512; Cw = 512; L = 256; rs = 512; co = 0;
    cblk = r & 7; lblk = (r >> 3) & 3; b = r >> 5;
  } else if (local < 384) {
    const int r = local - 320;
    src = lastcls; dst = cat; Cr = 498; Cw = 498; L = 64; rs = CATP; co = 2048;
    cblk = r & 7; lblk = 0; b = r >> 3;
  } else {
    const int r = local - 384;
    src = locres; dst = cat; Cr = 2; Cw = 14; L = 64; rs = CATP; co = 3570;
    cblk = 0; lblk = 0; b = r;
  }
  const int c0 = cblk * 64, l0 = lblk * 64;
  for (int e = threadIdx.x; e < 4096; e += 256) {
    const int cc = e >> 6, ll = e & 63;
    const int c = c0 + cc;
    tile[cc * 65 + ll] = (c < Cr) ? src[((size_t)b * Cr + c) * L + l0 + ll] : 0.f;
  }
  __syncthreads();
  for (int e = threadIdx.x; e < 4096; e += 256) {
    const int ll = e >> 6, cc = e & 63;
    const int c = c0 + cc;
    if (c < Cw)
      dst[((size_t)b * L + l0 + ll) * rs + co + c] = f2bf(tile[cc * 65 + ll]);
  }
}

// ---------------------------------------------------------------------------
// Row-split fused GEMM + GroupNorm + ReLU body (unchanged).
// ---------------------------------------------------------------------------
__device__ void gemm_gn_body(const ushort* __restrict__ Xt,
                             const ushort* __restrict__ Wb,
                             const float* __restrict__ bias,
                             const float* __restrict__ gamma,
                             const float* __restrict__ beta, int Kp,
                             int cpgShift, float* __restrict__ outF, int outFM,
                             ushort* __restrict__ catOut, int catStride,
                             int chOff, int ot, int b, float* smem) {
  float* red = smem;
  float* rs = smem + 4224;
  float* rss = smem + 4228;
  float* gmean = smem + 4232;
  float* grstd = smem + 4236;
  const int w = threadIdx.x >> 6;
  const int lane = threadIdx.x & 63;
  const int l15 = lane & 15, l4 = lane >> 4;
  const int o0 = ot * 64;

  f32x4 acc[4] = {};
  const ushort* wbase = Wb + (size_t)ot * (Kp >> 5) * 2048 + lane * 8;
  const ushort* bp[4];
#pragma unroll
  for (int j = 0; j < 4; j++)
    bp[j] = Xt + (size_t)(b * 64 + j * 16 + l15) * Kp + l4 * 8;
  const int nkc = Kp >> 5;
  for (int kc = 0; kc < nkc; kc++) {
    const short8 a = *(const short8*)(wbase + ((size_t)kc * 4 + w) * 512);
    short8 x[4];
#pragma unroll
    for (int j = 0; j < 4; j++) x[j] = *(const short8*)(bp[j] + kc * 32);
#pragma unroll
    for (int j = 0; j < 4; j++)
      acc[j] = __builtin_amdgcn_mfma_f32_16x16x32_bf16(a, x[j], acc[j], 0, 0, 0);
  }
#pragma unroll
  for (int j = 0; j < 4; j++)
#pragma unroll
    for (int r = 0; r < 4; r++) {
      const int m = w * 16 + l4 * 4 + r;
      red[m * 65 + j * 16 + l15] = acc[j][r] + bias[o0 + m];
    }
  __syncthreads();

  const int cpg = 1 << cpgShift;
  const int ngroups = 64 >> cpgShift;
  for (int gi = 0; gi < ngroups; gi++) {
    float s = 0.f, ss = 0.f;
    const int nel = cpg << 6;
    for (int e = threadIdx.x; e < nel; e += 256) {
      const float v = red[((gi << cpgShift) + (e >> 6)) * 65 + (e & 63)];
      s += v;
      ss += v * v;
    }
#pragma unroll
    for (int off = 32; off > 0; off >>= 1) {
      s += __shfl_down(s, off);
      ss += __shfl_down(ss, off);
    }
    if (lane == 0) { rs[w] = s; rss[w] = ss; }
    __syncthreads();
    if (threadIdx.x == 0) {
      const float ts = rs[0] + rs[1] + rs[2] + rs[3];
      const float tss = rss[0] + rss[1] + rss[2] + rss[3];
      const float mean = ts / (float)nel;
      const float var = tss / (float)nel - mean * mean;
      gmean[gi] = mean;
      grstd[gi] = rsqrtf(var + 1e-5f);
    }
    __syncthreads();
  }

  if (outF) {
    for (int e = threadIdx.x; e < 4096; e += 256) {
      const int m = e >> 6, n = e & 63;
      const int gi = m >> cpgShift;
      const int c = o0 + m;
      float v = (red[m * 65 + n] - gmean[gi]) * grstd[gi] * gamma[c] + beta[c];
      v = fmaxf(v, 0.f);
      outF[((size_t)b * outFM + c) * 64 + n] = v;
    }
  }
  if (catOut) {
    for (int e = threadIdx.x; e < 4096; e += 256) {
      const int n = e >> 6, m = e & 63;
      const int gi = m >> cpgShift;
      const int c = o0 + m;
      float v = (red[m * 65 + n] - gmean[gi]) * grstd[gi] * gamma[c] + beta[c];
      v = fmaxf(v, 0.f);
      catOut[((size_t)(b * 64) + n) * catStride + chOff + c] = f2bf(v);
    }
  }
}

// ---------------------------------------------------------------------------
// Row-split final-projection partial (unchanged). P: [slice][b][o(512)][t(64)]
// ---------------------------------------------------------------------------
__device__ void gemm_part_body(const ushort* __restrict__ Xt,
                               const ushort* __restrict__ Wb,
                               float* __restrict__ P, int ot, int b, int slice,
                               int kbeg, int kend) {
  const int w = threadIdx.x >> 6;
  const int lane = threadIdx.x & 63;
  const int l15 = lane & 15, l4 = lane >> 4;
  f32x4 acc[4] = {};
  const ushort* wbase = Wb + (size_t)ot * (CATP >> 5) * 2048 + lane * 8;
  const ushort* bp[4];
#pragma unroll
  for (int j = 0; j < 4; j++)
    bp[j] = Xt + (size_t)(b * 64 + j * 16 + l15) * CATP + l4 * 8;
  for (int k = kbeg; k < kend; k += 32) {
    const int kc = k >> 5;
    const short8 a = *(const short8*)(wbase + ((size_t)kc * 4 + w) * 512);
    short8 x[4];
#pragma unroll
    for (int j = 0; j < 4; j++) x[j] = *(const short8*)(bp[j] + k);
#pragma unroll
    for (int j = 0; j < 4; j++)
      acc[j] = __builtin_amdgcn_mfma_f32_16x16x32_bf16(a, x[j], acc[j], 0, 0, 0);
  }
  float* Pp = P + (((size_t)slice * BB + b) * 512 + ot * 64) * 64;
#pragma unroll
  for (int j = 0; j < 4; j++)
#pragma unroll
    for (int r = 0; r < 4; r++)
      Pp[(w * 16 + l4 * 4 + r) * 64 + j * 16 + l15] = acc[j][r];
}

// ---------------------------------------------------------------------------
// Final projection: fused last-K GEMM (K in [2528,3584)) + 4-slice reduce +
// bias + GN + ReLU -> out_main f32. grid (8,8).
// ---------------------------------------------------------------------------
__global__ __launch_bounds__(256) void reduce_gn_kernel(
    const ushort* __restrict__ cat, const ushort* __restrict__ Wprop,
    const float* __restrict__ P, const float* __restrict__ bias,
    const float* __restrict__ gamma, const float* __restrict__ beta,
    float* __restrict__ outF) {
  const int ot = blockIdx.x;
  const int b = blockIdx.y;
  const int o0 = ot * 64;
  const int w = threadIdx.x >> 6;
  const int lane = threadIdx.x & 63;
  const int l15 = lane & 15, l4 = lane >> 4;

  f32x4 acc[4] = {};
  const ushort* wbase = Wprop + (size_t)ot * (CATP >> 5) * 2048 + lane * 8;
  const ushort* bp[4];
#pragma unroll
  for (int j = 0; j < 4; j++)
    bp[j] = cat + (size_t)(b * 64 + j * 16 + l15) * CATP + l4 * 8;
  for (int k = 2528; k < 3584; k += 32) {
    const int kc = k >> 5;
    const short8 a = *(const short8*)(wbase + ((size_t)kc * 4 + w) * 512);
    short8 x[4];
#pragma unroll
    for (int j = 0; j < 4; j++) x[j] = *(const short8*)(bp[j] + k);
#pragma unroll
    for (int j = 0; j < 4; j++)
      acc[j] = __builtin_amdgcn_mfma_f32_16x16x32_bf16(a, x[j], acc[j], 0, 0, 0);
  }

  __shared__ float red[64 * 65];
#pragma unroll
  for (int j = 0; j < 4; j++)
#pragma unroll
    for (int r = 0; r < 4; r++)
      red[(w * 16 + l4 * 4 + r) * 65 + j * 16 + l15] = acc[j][r];
  __syncthreads();
  for (int e = threadIdx.x; e < 4096; e += 256) {
    const int m = e >> 6, n = e & 63;
    float s = bias[o0 + m];
#pragma unroll
    for (int z = 0; z < 4; z++)
      s += P[(((size_t)z * BB + b) * 512 + o0 + m) * 64 + n];
    red[m * 65 + n] += s;
  }
  __syncthreads();
  __shared__ float rs[4], rss[4], gmean[4], grstd[4];
  for (int gi = 0; gi < 4; gi++) {
    float s = 0.f, ss = 0.f;
    for (int e = threadIdx.x; e < 1024; e += 256) {
      const float v = red[((gi << 4) + (e >> 6)) * 65 + (e & 63)];
      s += v;
      ss += v * v;
    }
#pragma unroll
    for (int off = 32; off > 0; off >>= 1) {
      s += __shfl_down(s, off);
      ss += __shfl_down(ss, off);
    }
    if (lane == 0) { rs[w] = s; rss[w] = ss; }
    __syncthreads();
    if (threadIdx.x == 0) {
      const float ts = rs[0] + rs[1] + rs[2] + rs[3];
      const float tss = rss[0] + rss[1] + rss[2] + rss[3];
      const float mean = ts / 1024.f;
      const float var = tss / 1024.f - mean * mean;
      gmean[gi] = mean;
      grstd[gi] = rsqrtf(var + 1e-5f);
    }
    __syncthreads();
  }
  for (int e = threadIdx.x; e < 4096; e += 256) {
    const int m = e >> 6, n = e & 63;
    const int gi = m >> 4;
    const int c = o0 + m;
    float v = (red[m * 65 + n] - gmean[gi]) * grstd[gi] * gamma[c] + beta[c];
    outF[((size_t)b * 512 + c) * 64 + n] = fmaxf(v, 0.f);
  }
}

// ---------------------------------------------------------------------------
// BoundaryMaxPooling body on transposed bf16 (unchanged).
// ---------------------------------------------------------------------------
template <int C, int L>
__device__ void bmp_body(const ushort* __restrict__ Xt,
                         const int* __restrict__ segs, ushort* __restrict__ Y,
                         int rowStride, int chOff, int t, int b,
                         float2 (*pmax)[512]) {
  constexpr int C2 = C / 2;
  constexpr int P2 = C2 / 2;
  constexpr int CH = P2 / 64;
  const int w = threadIdx.x >> 6;
  const int lane = threadIdx.x & 63;
  const int* sg = segs + ((size_t)b * 64 + t) * 4;
  const ushort* Xb = Xt + (size_t)b * L * C;
#pragma unroll
  for (int h = 0; h < 2; h++) {
    const int s = min(max(sg[2 * h], 0), L - 1);
    const int e = max(min(max(sg[2 * h + 1], 0), L - 1), s);
#pragma unroll
    for (int q = 0; q < CH; q++) {
      const int p = q * 64 + lane;
      const ushort* base = Xb + h * C2 + 2 * p;
      float a0 = -INFINITY, a1 = -INFINITY;
      float c0 = -INFINITY, c1 = -INFINITY;
      int l = s + w;
      for (; l + 4 <= e; l += 8) {
        const unsigned u0 = *(const unsigned*)(base + (size_t)l * C);
        const unsigned u1 = *(const unsigned*)(base + (size_t)(l + 4) * C);
        a0 = fmaxf(a0, bf2f(u0 & 0xffffu));
        a1 = fmaxf(a1, bf2f(u0 >> 16));
        c0 = fmaxf(c0, bf2f(u1 & 0xffffu));
        c1 = fmaxf(c1, bf2f(u1 >> 16));
      }
      if (l <= e) {
        const unsigned u0 = *(const unsigned*)(base + (size_t)l * C);
        a0 = fmaxf(a0, bf2f(u0 & 0xffffu));
        a1 = fmaxf(a1, bf2f(u0 >> 16));
      }
      pmax[w][h * P2 + p] = make_float2(fmaxf(a0, c0), fmaxf(a1, c1));
    }
  }
  __syncthreads();
  for (int idx = threadIdx.x; idx < 2 * P2; idx += 256) {
    float2 m = pmax[0][idx];
#pragma unroll
    for (int ww = 1; ww < 4; ww++) {
      const float2 v = pmax[ww][idx];
      m.x = fmaxf(m.x, v.x);
      m.y = fmaxf(m.y, v.y);
    }
    const unsigned o = (unsigned)f2bf(m.x) | ((unsigned)f2bf(m.y) << 16);
    *(unsigned*)(Y + ((size_t)(b * 64) + t) * rowStride + chOff + 2 * idx) = o;
  }
}

// ---------------------------------------------------------------------------
// Batch-grouped anchor-conv MFMA: one (nt, tap, c-span) weight tile reused
// across BG batches. Per chunk: 4 wt + BG act loads -> 4*BG MFMA (ratio 2.0
// at BG=4, 16-way MFMA ILP). Direct P store [slice][b][t(64)][o(512)].
// ---------------------------------------------------------------------------
template <int Kf, int L, int Cin, int CSPAN, int BG>
__device__ void anchor_body3(const ushort* __restrict__ src,
                             const int* __restrict__ anc,
                             const ushort* __restrict__ Wt,
                             float* __restrict__ P, int nt, int b0, int k,
                             int cbase, int slice) {
  const int w = threadIdx.x >> 6;
  const int lane = threadIdx.x & 63;
  const int l15 = lane & 15, l4 = lane >> 4;
  const int t = w * 16 + l15;

  const ushort* rp[BG];
#pragma unroll
  for (int bi = 0; bi < BG; bi++) {
    const int b = b0 + bi;
    const int a0 = anc[((size_t)b * 64 + t) * 2 + 0];
    const int a1 = anc[((size_t)b * 64 + t) * 2 + 1];
    const int left = min(max(a0, 0), L);
    const int right = min(max(a1, 0), L);
    const int seglen = right + 1 - left;
    const int ix = min(max(left + (k * seglen) / Kf, 0), L - 1);
    rp[bi] = src + ((size_t)b * L + ix) * Cin + cbase + l4 * 8;
  }
  const ushort* wb = Wt + ((size_t)nt * Kf + k) * (Cin >> 5) * 2048 + lane * 8;

  f32x4 acc[BG][4] = {};
#pragma unroll 2
  for (int c0 = 0; c0 < CSPAN; c0 += 32) {
    const int cc = (cbase + c0) >> 5;
    short8 bbf[4];
#pragma unroll
    for (int j = 0; j < 4; j++)
      bbf[j] = *(const short8*)(wb + ((size_t)cc * 4 + j) * 512);
    short8 a[BG];
#pragma unroll
    for (int bi = 0; bi < BG; bi++) a[bi] = *(const short8*)(rp[bi] + c0);
#pragma unroll
    for (int bi = 0; bi < BG; bi++)
#pragma unroll
      for (int j = 0; j < 4; j++)
        acc[bi][j] = __builtin_amdgcn_mfma_f32_16x16x32_bf16(a[bi], bbf[j],
                                                             acc[bi][j], 0, 0, 0);
  }
#pragma unroll
  for (int bi = 0; bi < BG; bi++) {
    float* Pp = P + (((size_t)slice * BB + b0 + bi) * 64) * 512 + nt * 64;
#pragma unroll
    for (int j = 0; j < 4; j++)
#pragma unroll
      for (int r = 0; r < 4; r++)
        Pp[(size_t)(w * 16 + l4 * 4 + r) * 512 + j * 16 + l15] = acc[bi][j][r];
  }
}

// ---------------------------------------------------------------------------
// Anchor split-K reduce + valid mask + bias -> bf16 transposed rows.
// ---------------------------------------------------------------------------
__device__ void anchor_reduce_body(const float* __restrict__ P, int ks,
                                   const float* __restrict__ bias,
                                   const int* __restrict__ anc, int L,
                                   ushort* __restrict__ Y, int rowStride,
                                   int chOff, int ot, int b, float* smem) {
  float* tile = smem;
  float* sval = smem + 4160;
  const int o0 = ot * 64;
  if (threadIdx.x < 64) {
    const int t = threadIdx.x;
    const int a0 = anc[((size_t)b * 64 + t) * 2 + 0];
    const int a1 = anc[((size_t)b * 64 + t) * 2 + 1];
    const int left = min(max(a0, 0), L);
    const int right = min(max(a1, 0), L);
    sval[t] = (right > left) ? 1.f : 0.f;
  }
  __syncthreads();
  for (int e = threadIdx.x; e < 4096; e += 256) {
    const int m = e >> 6, nl = e & 63;  // m = t, nl = o_local
    float s = 0.f;
    for (int z = 0; z < ks; z++)
      s += P[(((size_t)z * BB + b) * 64 + m) * 512 + o0 + nl];
    tile[nl * 65 + m] = s * sval[m] + bias[o0 + nl];
  }
  __syncthreads();
  for (int e = threadIdx.x; e < 4096; e += 256) {
    const int m = e >> 6, nl = e & 63;
    Y[((size_t)(b * 64) + m) * rowStride + chOff + o0 + nl] =
        f2bf(tile[nl * 65 + m]);
  }
}

// ---------------------------------------------------------------------------
// Fused launch B: needs only prep_early outputs.
//   [0,256)     anchor-conv frame BG=4 (8nt x 2bg x 16s) -> P0
//   [256,448)   fm_short + feat_lr GEMM+GN -> cat[1536:2048], feat_lr, FlrT
//   [448,960)   BMP frame                  -> XbmpT
//   [960,1088)  Wroi convert   (for C)
//   [1088,1984) Wprop convert  (for D/F)
//   [1984,2240) WcpT convert   (for C)
// ---------------------------------------------------------------------------
__global__ __launch_bounds__(256) void fused_B_kernel(
    const ushort* __restrict__ Ft, const ushort* __restrict__ Wcomb,
    const float* __restrict__ b_cur, const float* __restrict__ g_cur,
    const float* __restrict__ be_cur, ushort* __restrict__ cat,
    const float* __restrict__ b_lr, const float* __restrict__ g_lr,
    const float* __restrict__ be_lr, float* __restrict__ feat_lr,
    ushort* __restrict__ FlrT, const ushort* __restrict__ FfT,
    const int* __restrict__ frame_segs, ushort* __restrict__ XbmpT,
    const int* __restrict__ frame_anchor, const ushort* __restrict__ Wcp0T,
    float* __restrict__ P0, const float* __restrict__ w_roi,
    ushort* __restrict__ Wroi, const float* __restrict__ w_prop,
    ushort* __restrict__ Wprop, const float* __restrict__ w_cp,
    ushort* __restrict__ WcpT) {
  __shared__ __align__(16) float smem[4240];
  const int bid = blockIdx.x;
  if (bid < 256) {
    const int nt = bid & 7, bg = (bid >> 3) & 1, s = bid >> 4;  // s in [0,16)
    anchor_body3<8, 256, 512, 256, 4>(FfT, frame_anchor, Wcp0T, P0, nt,
                                      bg * 4, s >> 1, (s & 1) * 256, s);
  } else if (bid < 448) {
    const int r = bid - 256;
    const int b = r / 24, ot24 = r % 24;
    if (ot24 < 8)
      gemm_gn_body(Ft, Wcomb, b_cur, g_cur, be_cur, 512, 4, nullptr, 0, cat,
                   CATP, 1536, ot24, b, smem);
    else
      gemm_gn_body(Ft, Wcomb + 512 * 512, b_lr, g_lr, be_lr, 512, 5, feat_lr,
                   1024, FlrT, 1024, 0, ot24 - 8, b, smem);
  } else if (bid < 960) {
    const int r = bid - 448;
    bmp_body<512, 256>(FfT, frame_segs, XbmpT, 512, 0, r & 63, r >> 6,
                       (float2(*)[512])smem);
  } else if (bid < 1088) {
    const int r = (bid - 960) * 256 + threadIdx.x;  // [0, 32768)
    wfrag_conv(w_roi + (size_t)(r >> 6) * 512, Wroi, r >> 6, r & 63, 16, 0);
  } else if (bid < 1984) {
    const int r = (bid - 1088) * 256 + threadIdx.x;  // [0, 229376)
    wfrag_conv(w_prop + (size_t)(r / 448) * CAT_REAL, Wprop, r / 448, r % 448,
               112, CAT_REAL);
  } else {
    const int local = bid - 1984;  // [0,256)
    cpT_tile<1024, 16>(w_cp, WcpT, local >> 5, local & 31);
  }
}

// ---------------------------------------------------------------------------
// Fused launch C: needs B outputs.
//   [0,512)    anchor-conv con BG=4 (8nt x 2bg x 32s) -> P1
//   [512,576)  prop_roi GEMM+GN        -> cat[0:512]
//   [576,640)  frame reduce (16 slices)-> FconT
//   [640,1152) BMP con                 -> cat[512:1536]
// ---------------------------------------------------------------------------
__global__ __launch_bounds__(256) void fused_C_kernel(
    const ushort* __restrict__ FlrT, const int* __restrict__ segments,
    ushort* __restrict__ cat, const int* __restrict__ anchor,
    const ushort* __restrict__ WcpT, float* __restrict__ P1,
    const float* __restrict__ P0, const float* __restrict__ b_cp0,
    const int* __restrict__ frame_anchor, ushort* __restrict__ FconT,
    const ushort* __restrict__ XbmpT, const ushort* __restrict__ Wroi,
    const float* __restrict__ b_roi, const float* __restrict__ g_roi,
    const float* __restrict__ be_roi) {
  __shared__ __align__(16) float smem[4240];
  const int bid = blockIdx.x;
  if (bid < 512) {
    const int nt = bid & 7, bg = (bid >> 3) & 1, s = bid >> 4;  // s in [0,32)
    anchor_body3<16, 64, 1024, 512, 4>(FlrT, anchor, WcpT, P1, nt, bg * 4,
                                       s >> 1, (s & 1) * 512, s);
  } else if (bid < 576) {
    const int r = bid - 512;
    gemm_gn_body(XbmpT, Wroi, b_roi, g_roi, be_roi, 512, 4, nullptr, 0, cat,
                 CATP, 0, r & 7, r >> 3, smem);
  } else if (bid < 640) {
    const int r = bid - 576;
    anchor_reduce_body(P0, 16, b_cp0, frame_anchor, 256, FconT, 512, 0, r & 7,
                       r >> 3, smem);
  } else {
    const int r = bid - 640;
    bmp_body<1024, 64>(FlrT, segments, cat, CATP, 512, r & 63, r >> 6,
                       (float2(*)[512])smem);
  }
}

// ---------------------------------------------------------------------------
// Fused launch D: needs C outputs.
//   [0,256)   final-proj partials over ready cat cols [0,2528), 4 slices
//   [256,320) con reduce (32 slices)  -> cat[2546:3058]
//   [320,384) prop_con GEMM+GN        -> cat[3058:3570]
// ---------------------------------------------------------------------------
__global__ __launch_bounds__(256) void fused_D_kernel(
    const ushort* __restrict__ cat, const ushort* __restrict__ Wprop,
    float* __restrict__ P9, const float* __restrict__ P1,
    const float* __restrict__ b_cp, const int* __restrict__ anchor,
    ushort* __restrict__ catw, const ushort* __restrict__ FconT,
    const ushort* __restrict__ Wroi, const float* __restrict__ b_roi,
    const float* __restrict__ g_roi, const float* __restrict__ be_roi) {
  __shared__ __align__(16) float smem[4240];
  const int bid = blockIdx.x;
  if (bid < 256) {
    const int s = bid >> 6, q = bid & 63;
    const int kb = s * 640;
    const int ke = (s == 3) ? 2528 : kb + 640;
    gemm_part_body(cat, Wprop, P9, q & 7, q >> 3, s, kb, ke);
  } else if (bid < 320) {
    const int r = bid - 256;
    anchor_reduce_body(P1, 32, b_cp, anchor, 64, catw, CATP, 2546, r & 7,
                       r >> 3, smem);
  } else {
    const int r = bid - 320;
    gemm_gn_body(FconT, Wroi, b_roi, g_roi, be_roi, 512, 4, nullptr, 0, catw,
                 CATP, 3058, r & 7, r >> 3, smem);
  }
}

extern "C" void kernel_launch(void* const* d_in, const int* in_sizes, int n_in,
                              void* d_out, int out_size, void* d_ws,
                              size_t ws_size, hipStream_t stream) {
  const float* feature      = (const float*)d_in[0];
  const float* frame_feat   = (const float*)d_in[1];
  const int*   segments     = (const int*)d_in[2];
  const int*   frame_segs   = (const int*)d_in[3];
  const float* feat_lastcls = (const float*)d_in[4];
  const int*   anchor       = (const int*)d_in[5];
  const int*   frame_anchor = (const int*)d_in[6];
  const float* locres       = (const float*)d_in[8];
  const float* w_cur  = (const float*)d_in[9];
  const float* b_cur  = (const float*)d_in[10];
  const float* g_cur  = (const float*)d_in[11];
  const float* be_cur = (const float*)d_in[12];
  const float* w_lr   = (const float*)d_in[13];
  const float* b_lr   = (const float*)d_in[14];
  const float* g_lr   = (const float*)d_in[15];
  const float* be_lr  = (const float*)d_in[16];
  const float* w_roi  = (const float*)d_in[17];
  const float* b_roi  = (const float*)d_in[18];
  const float* g_roi  = (const float*)d_in[19];
  const float* be_roi = (const float*)d_in[20];
  const float* w_cp   = (const float*)d_in[21];  // [512,1024,16]
  const float* b_cp   = (const float*)d_in[22];
  const float* w_cp0  = (const float*)d_in[23];  // [512,512,8]
  const float* b_cp0  = (const float*)d_in[24];
  const float* w_prop = (const float*)d_in[25];  // [512,3572]
  const float* b_prop = (const float*)d_in[26];
  const float* g_prop = (const float*)d_in[27];
  const float* be_prop= (const float*)d_in[28];

  float* out_main = (float*)d_out;                  // [8,512,64]
  float* feat_lr  = (float*)d_out + BB * 512 * 64;  // [8,1024,64]

  // workspace layout (ushort units)
  ushort* cat_t  = (ushort*)d_ws;             // 1,835,008
  ushort* Ft     = cat_t + 1835008;           // 262,144
  ushort* XbmpT  = Ft + 262144;               // 262,144
  ushort* FconT  = XbmpT + 262144;            // 262,144
  ushort* Wcomb  = FconT + 262144;            // 786,432 (frag)
  ushort* Wroi   = Wcomb + 786432;            // 262,144 (frag)
  ushort* Wprop  = Wroi + 262144;             // 1,835,008 (frag)
  ushort* WcpT   = Wprop + 1835008;           // 8,388,608 (frag)
  ushort* Wcp0T  = WcpT + 8388608;            // 2,097,152 (frag)
  ushort* FlrT   = Wcp0T + 2097152;           // 524,288  [8*64][1024]
  ushort* FfT    = FlrT + 524288;             // 1,048,576 [8*256][512]
  float*  P1     = (float*)(FfT + 1048576);   // 8,388,608 f (32 slices [s][b][t][o])
  float*  P0     = P1 + 8388608;              // 4,194,304 f (16 slices [s][b][t][o])
  float*  P9     = P0 + 4194304;              // 1,048,576 f (4 slices [s][b][o][t])
  // total ~90 MB (fill shows workspace >= 256 MB)

  // A: minimal prep (only what B needs)
  prep_early_kernel<<<904, 256, 0, stream>>>(
      w_cur, w_lr, Wcomb, w_cp0, Wcp0T, feature, frame_feat, feat_lastcls,
      locres, Ft, FfT, cat_t);

  // B: frame anchor-conv BG=4 | GEMM+GN | frame BMP | Wroi/Wprop/WcpT converts
  fused_B_kernel<<<2240, 256, 0, stream>>>(
      Ft, Wcomb, b_cur, g_cur, be_cur, cat_t, b_lr, g_lr, be_lr, feat_lr,
      FlrT, FfT, frame_segs, XbmpT, frame_anchor, Wcp0T, P0, w_roi, Wroi,
      w_prop, Wprop, w_cp, WcpT);

  // C: con anchor-conv BG=4 | prop_roi | frame reduce -> FconT | con BMP
  fused_C_kernel<<<1152, 256, 0, stream>>>(
      FlrT, segments, cat_t, anchor, WcpT, P1, P0, b_cp0, frame_anchor, FconT,
      XbmpT, Wroi, b_roi, g_roi, be_roi);

  // D: final-proj partials K<2528 | con reduce (32) -> cat | prop_con
  fused_D_kernel<<<384, 256, 0, stream>>>(
      cat_t, Wprop, P9, P1, b_cp, anchor, cat_t, FconT, Wroi, b_roi, g_roi,
      be_roi);

  // F: last-K GEMM + reduce + bias + GN + ReLU -> out_main
  reduce_gn_kernel<<<dim3(8, BB), 256, 0, stream>>>(
      cat_t, Wprop, P9, b_prop, g_prop, be_prop, out_main);
}

// Round 4
// 310.620 us; speedup vs baseline: 1.1263x; 1.1263x over previous
//
#include <hip/hip_runtime.h>
#include <math.h>

#define BB 8
#define CATP 3584   // padded cat K (3572 -> 3584, zeros)
#define CAT_REAL 3572

typedef __attribute__((ext_vector_type(8))) short short8;
typedef __attribute__((ext_vector_type(4))) float f32x4;

__device__ inline ushort f2bf(float f) {
  union { float f; unsigned u; } x;
  x.f = f;
  return (ushort)((x.u + 0x7FFFu + ((x.u >> 16) & 1u)) >> 16);
}
__device__ inline float bf2f(unsigned us) {
  union { unsigned u; float f; } x;
  x.u = us << 16;
  return x.f;
}

// ---------------------------------------------------------------------------
// PREP (one launch, round-0 verbatim): dense weight frags + anchor conv
// weight frags + all activation transposes.
// ---------------------------------------------------------------------------
template <int Cin, int Kf>
__device__ void cpT_tile(const float* __restrict__ W, ushort* __restrict__ D,
                         int nt, int cc) {
  const int tid = threadIdx.x;
  const int j = tid >> 6, l4 = (tid >> 4) & 3, l15 = tid & 15;
  const int o = nt * 64 + j * 16 + l15;
  const int cb = cc * 32 + l4 * 8;
  ushort rg[8][Kf];
#pragma unroll
  for (int q = 0; q < 8; q++) {
    const float* row = W + ((size_t)o * Cin + cb + q) * Kf;
#pragma unroll
    for (int kq = 0; kq < Kf / 4; kq++) {
      const float4 f = *(const float4*)(row + kq * 4);
      rg[q][kq * 4 + 0] = f2bf(f.x);
      rg[q][kq * 4 + 1] = f2bf(f.y);
      rg[q][kq * 4 + 2] = f2bf(f.z);
      rg[q][kq * 4 + 3] = f2bf(f.w);
    }
  }
#pragma unroll
  for (int k = 0; k < Kf; k++) {
    uint4 pk;
    pk.x = (unsigned)rg[0][k] | ((unsigned)rg[1][k] << 16);
    pk.y = (unsigned)rg[2][k] | ((unsigned)rg[3][k] << 16);
    pk.z = (unsigned)rg[4][k] | ((unsigned)rg[5][k] << 16);
    pk.w = (unsigned)rg[6][k] | ((unsigned)rg[7][k] << 16);
    *(uint4*)(D + ((size_t)(nt * Kf + k) * (Cin >> 5) + cc) * 2048 + tid * 8) = pk;
  }
}

__global__ __launch_bounds__(256) void prep_kernel(
    const float* __restrict__ w_cur, const float* __restrict__ w_lr,
    const float* __restrict__ w_roi, const float* __restrict__ w_prop,
    ushort* __restrict__ Wcomb, ushort* __restrict__ Wroi,
    ushort* __restrict__ Wprop, const float* __restrict__ w_cp,
    ushort* __restrict__ WcpT, const float* __restrict__ w_cp0,
    ushort* __restrict__ Wcp0T, const float* __restrict__ feature,
    const float* __restrict__ frame_feat, const float* __restrict__ lastcls,
    const float* __restrict__ locres, ushort* __restrict__ Ft,
    ushort* __restrict__ FfT, ushort* __restrict__ cat) {
  __shared__ float tile[64 * 65];
  const int bid = blockIdx.x;
  if (bid < 1408) {
    const int i = bid * 256 + threadIdx.x;
    const float* src;
    ushort* dst;
    int o, k8, Kc;
    bool pad = false;
    if (i < 98304) {
      o = i >> 6; k8 = i & 63; Kc = 16;
      src = (o < 512) ? (w_cur + (size_t)o * 512)
                      : (w_lr + (size_t)(o - 512) * 512);
      dst = Wcomb;
    } else if (i < 131072) {
      const int r = i - 98304;
      o = r >> 6; k8 = r & 63; Kc = 16;
      src = w_roi + (size_t)o * 512;
      dst = Wroi;
    } else {
      const int r = i - 131072;
      if (r >= 229376) return;
      o = r / 448; k8 = r % 448; Kc = 112;
      src = w_prop + (size_t)o * CAT_REAL;
      dst = Wprop;
      pad = true;
    }
    const int k = k8 * 8;
    float v[8];
    if (pad) {
#pragma unroll
      for (int q = 0; q < 8; q++) v[q] = (k + q < CAT_REAL) ? src[k + q] : 0.f;
    } else {
      const float4 f0 = *(const float4*)(src + k);
      const float4 f1 = *(const float4*)(src + k + 4);
      v[0] = f0.x; v[1] = f0.y; v[2] = f0.z; v[3] = f0.w;
      v[4] = f1.x; v[5] = f1.y; v[6] = f1.z; v[7] = f1.w;
    }
    uint4 pk;
    pk.x = (unsigned)f2bf(v[0]) | ((unsigned)f2bf(v[1]) << 16);
    pk.y = (unsigned)f2bf(v[2]) | ((unsigned)f2bf(v[3]) << 16);
    pk.z = (unsigned)f2bf(v[4]) | ((unsigned)f2bf(v[5]) << 16);
    pk.w = (unsigned)f2bf(v[6]) | ((unsigned)f2bf(v[7]) << 16);
    const int ot = o >> 6, ii = (o >> 4) & 3, l15 = o & 15;
    const int kc = k8 >> 2, l4 = k8 & 3;
    const size_t flat =
        ((((size_t)ot * Kc + kc) * 4 + ii) * 64 + l4 * 16 + l15) * 8;
    *(uint4*)(dst + flat) = pk;
    return;
  }
  if (bid < 1792) {
    const int local = bid - 1408;
    if (local < 256)
      cpT_tile<1024, 16>(w_cp, WcpT, local >> 5, local & 31);
    else {
      const int r = local - 256;
      cpT_tile<512, 8>(w_cp0, Wcp0T, r >> 4, r & 15);
    }
    return;
  }
  const int local = bid - 1792;
  const float* src;
  ushort* dst;
  int Cr, Cw, L, rs, co, cblk, lblk, b;
  if (local < 64) {
    src = feature; dst = Ft; Cr = 512; Cw = 512; L = 64; rs = 512; co = 0;
    cblk = local & 7; lblk = 0; b = local >> 3;
  } else if (local < 320) {
    const int r = local - 64;
    src = frame_feat; dst = FfT; Cr = 512; Cw = 512; L = 256; rs = 512; co = 0;
    cblk = r & 7; lblk = (r >> 3) & 3; b = r >> 5;
  } else if (local < 384) {
    const int r = local - 320;
    src = lastcls; dst = cat; Cr = 498; Cw = 498; L = 64; rs = CATP; co = 2048;
    cblk = r & 7; lblk = 0; b = r >> 3;
  } else {
    const int r = local - 384;
    src = locres; dst = cat; Cr = 2; Cw = 14; L = 64; rs = CATP; co = 3570;
    cblk = 0; lblk = 0; b = r;
  }
  const int c0 = cblk * 64, l0 = lblk * 64;
  for (int e = threadIdx.x; e < 4096; e += 256) {
    const int cc = e >> 6, ll = e & 63;
    const int c = c0 + cc;
    tile[cc * 65 + ll] = (c < Cr) ? src[((size_t)b * Cr + c) * L + l0 + ll] : 0.f;
  }
  __syncthreads();
  for (int e = threadIdx.x; e < 4096; e += 256) {
    const int ll = e >> 6, cc = e & 63;
    const int c = c0 + cc;
    if (c < Cw)
      dst[((size_t)b * L + l0 + ll) * rs + co + c] = f2bf(tile[cc * 65 + ll]);
  }
}

// ---------------------------------------------------------------------------
// ORIGINAL (round-0) 4-wave K-split fused GEMM + GroupNorm + ReLU body.
// Ratio 2.0 (8 loads / 16 MFMA), acc[4][4] ILP, 4-round LDS accumulate.
// ---------------------------------------------------------------------------
__device__ void gemm_gn_body(const ushort* __restrict__ Xt,
                             const ushort* __restrict__ Wb,
                             const float* __restrict__ bias,
                             const float* __restrict__ gamma,
                             const float* __restrict__ beta, int Kp,
                             int cpgShift, float* __restrict__ outF, int outFM,
                             ushort* __restrict__ catOut, int catStride,
                             int chOff, int ot, int b, float* smem) {
  float* red = smem;
  float* rs = smem + 4224;
  float* rss = smem + 4228;
  float* gmean = smem + 4232;
  float* grstd = smem + 4236;
  const int w = threadIdx.x >> 6;
  const int lane = threadIdx.x & 63;
  const int l15 = lane & 15, l4 = lane >> 4;
  const int o0 = ot * 64;
  const int wk = Kp >> 2;
  const int kbeg = w * wk, kend = kbeg + wk;

  f32x4 acc[4][4] = {};
  const ushort* wbase = Wb + (size_t)ot * (Kp >> 5) * 2048 + lane * 8;
  const ushort* bp[4];
#pragma unroll
  for (int j = 0; j < 4; j++)
    bp[j] = Xt + (size_t)(b * 64 + j * 16 + l15) * Kp + l4 * 8;

  for (int k = kbeg; k < kend; k += 32) {
    const int kc = k >> 5;
    short8 a[4], x[4];
#pragma unroll
    for (int i = 0; i < 4; i++)
      a[i] = *(const short8*)(wbase + ((size_t)kc * 4 + i) * 512);
#pragma unroll
    for (int j = 0; j < 4; j++) x[j] = *(const short8*)(bp[j] + k);
#pragma unroll
    for (int i = 0; i < 4; i++)
#pragma unroll
      for (int j = 0; j < 4; j++)
        acc[i][j] = __builtin_amdgcn_mfma_f32_16x16x32_bf16(a[i], x[j],
                                                            acc[i][j], 0, 0, 0);
  }

  for (int ww = 0; ww < 4; ww++) {
    __syncthreads();
    if (w == ww) {
#pragma unroll
      for (int i = 0; i < 4; i++)
#pragma unroll
        for (int j = 0; j < 4; j++)
#pragma unroll
          for (int r = 0; r < 4; r++) {
            const int m = i * 16 + l4 * 4 + r;
            const int n = j * 16 + l15;
            if (ww == 0)
              red[m * 65 + n] = acc[i][j][r] + bias[o0 + m];
            else
              red[m * 65 + n] += acc[i][j][r];
          }
    }
  }
  __syncthreads();

  const int cpg = 1 << cpgShift;
  const int ngroups = 64 >> cpgShift;
  for (int gi = 0; gi < ngroups; gi++) {
    float s = 0.f, ss = 0.f;
    const int nel = cpg << 6;
    for (int e = threadIdx.x; e < nel; e += 256) {
      const float v = red[((gi << cpgShift) + (e >> 6)) * 65 + (e & 63)];
      s += v;
      ss += v * v;
    }
#pragma unroll
    for (int off = 32; off > 0; off >>= 1) {
      s += __shfl_down(s, off);
      ss += __shfl_down(ss, off);
    }
    if (lane == 0) { rs[w] = s; rss[w] = ss; }
    __syncthreads();
    if (threadIdx.x == 0) {
      const float ts = rs[0] + rs[1] + rs[2] + rs[3];
      const float tss = rss[0] + rss[1] + rss[2] + rss[3];
      const float mean = ts / (float)nel;
      const float var = tss / (float)nel - mean * mean;
      gmean[gi] = mean;
      grstd[gi] = rsqrtf(var + 1e-5f);
    }
    __syncthreads();
  }

  if (outF) {
    for (int e = threadIdx.x; e < 4096; e += 256) {
      const int m = e >> 6, n = e & 63;
      const int gi = m >> cpgShift;
      const int c = o0 + m;
      float v = (red[m * 65 + n] - gmean[gi]) * grstd[gi] * gamma[c] + beta[c];
      v = fmaxf(v, 0.f);
      outF[((size_t)b * outFM + c) * 64 + n] = v;
    }
  }
  if (catOut) {
    for (int e = threadIdx.x; e < 4096; e += 256) {
      const int n = e >> 6, m = e & 63;
      const int gi = m >> cpgShift;
      const int c = o0 + m;
      float v = (red[m * 65 + n] - gmean[gi]) * grstd[gi] * gamma[c] + beta[c];
      v = fmaxf(v, 0.f);
      catOut[((size_t)(b * 64) + n) * catStride + chOff + c] = f2bf(v);
    }
  }
}

// ---------------------------------------------------------------------------
// ORIGINAL final-projection partial body, interleaved-kc 4-wave K-split over
// [kc0,kc1). P layout [slice][b][o(512)][t(64)].
// ---------------------------------------------------------------------------
__device__ void gemm_part_body(const ushort* __restrict__ Xt,
                               const ushort* __restrict__ Wb,
                               float* __restrict__ P, int ot, int b, int slice,
                               int kc0, int kc1, float* red) {
  const int w = threadIdx.x >> 6;
  const int lane = threadIdx.x & 63;
  const int l15 = lane & 15, l4 = lane >> 4;

  f32x4 acc[4][4] = {};
  const ushort* wbase = Wb + (size_t)ot * (CATP >> 5) * 2048 + lane * 8;
  const ushort* bp[4];
#pragma unroll
  for (int j = 0; j < 4; j++)
    bp[j] = Xt + (size_t)(b * 64 + j * 16 + l15) * CATP + l4 * 8;

  for (int kc = kc0 + w; kc < kc1; kc += 4) {
    short8 a[4], x[4];
#pragma unroll
    for (int i = 0; i < 4; i++)
      a[i] = *(const short8*)(wbase + ((size_t)kc * 4 + i) * 512);
#pragma unroll
    for (int j = 0; j < 4; j++) x[j] = *(const short8*)(bp[j] + kc * 32);
#pragma unroll
    for (int i = 0; i < 4; i++)
#pragma unroll
      for (int j = 0; j < 4; j++)
        acc[i][j] = __builtin_amdgcn_mfma_f32_16x16x32_bf16(a[i], x[j],
                                                            acc[i][j], 0, 0, 0);
  }

  for (int ww = 0; ww < 4; ww++) {
    __syncthreads();
    if (w == ww) {
#pragma unroll
      for (int i = 0; i < 4; i++)
#pragma unroll
        for (int j = 0; j < 4; j++)
#pragma unroll
          for (int r = 0; r < 4; r++) {
            const int m = i * 16 + l4 * 4 + r;
            const int n = j * 16 + l15;
            if (ww == 0)
              red[m * 65 + n] = acc[i][j][r];
            else
              red[m * 65 + n] += acc[i][j][r];
          }
    }
  }
  __syncthreads();
  float* Pp = P + (((size_t)slice * BB + b) * 512 + ot * 64) * 64;
  for (int e = threadIdx.x; e < 4096; e += 256)
    Pp[e] = red[(e >> 6) * 65 + (e & 63)];
}

// ---------------------------------------------------------------------------
// F: fused last-K GEMM (kc in [79,112), 4-wave interleaved) + 3-slice reduce
// + bias + GN + ReLU -> out_main f32. grid (8,8).
// ---------------------------------------------------------------------------
__global__ __launch_bounds__(256) void reduce_gn_kernel(
    const ushort* __restrict__ cat, const ushort* __restrict__ Wprop,
    const float* __restrict__ P, const float* __restrict__ bias,
    const float* __restrict__ gamma, const float* __restrict__ beta,
    float* __restrict__ outF) {
  const int ot = blockIdx.x;
  const int b = blockIdx.y;
  const int o0 = ot * 64;
  const int w = threadIdx.x >> 6;
  const int lane = threadIdx.x & 63;
  const int l15 = lane & 15, l4 = lane >> 4;

  f32x4 acc[4][4] = {};
  const ushort* wbase = Wprop + (size_t)ot * (CATP >> 5) * 2048 + lane * 8;
  const ushort* bp[4];
#pragma unroll
  for (int j = 0; j < 4; j++)
    bp[j] = cat + (size_t)(b * 64 + j * 16 + l15) * CATP + l4 * 8;

  for (int kc = 79 + w; kc < 112; kc += 4) {
    short8 a[4], x[4];
#pragma unroll
    for (int i = 0; i < 4; i++)
      a[i] = *(const short8*)(wbase + ((size_t)kc * 4 + i) * 512);
#pragma unroll
    for (int j = 0; j < 4; j++) x[j] = *(const short8*)(bp[j] + kc * 32);
#pragma unroll
    for (int i = 0; i < 4; i++)
#pragma unroll
      for (int j = 0; j < 4; j++)
        acc[i][j] = __builtin_amdgcn_mfma_f32_16x16x32_bf16(a[i], x[j],
                                                            acc[i][j], 0, 0, 0);
  }

  __shared__ float red[64 * 65];
  for (int ww = 0; ww < 4; ww++) {
    __syncthreads();
    if (w == ww) {
#pragma unroll
      for (int i = 0; i < 4; i++)
#pragma unroll
        for (int j = 0; j < 4; j++)
#pragma unroll
          for (int r = 0; r < 4; r++) {
            const int m = i * 16 + l4 * 4 + r;
            const int n = j * 16 + l15;
            if (ww == 0)
              red[m * 65 + n] = acc[i][j][r];
            else
              red[m * 65 + n] += acc[i][j][r];
          }
    }
  }
  __syncthreads();
  for (int e = threadIdx.x; e < 4096; e += 256) {
    const int m = e >> 6, n = e & 63;
    float s = bias[o0 + m];
#pragma unroll
    for (int z = 0; z < 3; z++)
      s += P[(((size_t)z * BB + b) * 512 + o0 + m) * 64 + n];
    red[m * 65 + n] += s;
  }
  __syncthreads();
  __shared__ float rs[4], rss[4], gmean[4], grstd[4];
  for (int gi = 0; gi < 4; gi++) {
    float s = 0.f, ss = 0.f;
    for (int e = threadIdx.x; e < 1024; e += 256) {
      const float v = red[((gi << 4) + (e >> 6)) * 65 + (e & 63)];
      s += v;
      ss += v * v;
    }
#pragma unroll
    for (int off = 32; off > 0; off >>= 1) {
      s += __shfl_down(s, off);
      ss += __shfl_down(ss, off);
    }
    if (lane == 0) { rs[w] = s; rss[w] = ss; }
    __syncthreads();
    if (threadIdx.x == 0) {
      const float ts = rs[0] + rs[1] + rs[2] + rs[3];
      const float tss = rss[0] + rss[1] + rss[2] + rss[3];
      const float mean = ts / 1024.f;
      const float var = tss / 1024.f - mean * mean;
      gmean[gi] = mean;
      grstd[gi] = rsqrtf(var + 1e-5f);
    }
    __syncthreads();
  }
  for (int e = threadIdx.x; e < 4096; e += 256) {
    const int m = e >> 6, n = e & 63;
    const int gi = m >> 4;
    const int c = o0 + m;
    float v = (red[m * 65 + n] - gmean[gi]) * grstd[gi] * gamma[c] + beta[c];
    outF[((size_t)b * 512 + c) * 64 + n] = fmaxf(v, 0.f);
  }
}

// ---------------------------------------------------------------------------
// BoundaryMaxPooling body on transposed bf16 (round-0 logic).
// ---------------------------------------------------------------------------
template <int C, int L>
__device__ void bmp_body(const ushort* __restrict__ Xt,
                         const int* __restrict__ segs, ushort* __restrict__ Y,
                         int rowStride, int chOff, int t, int b,
                         float2 (*pmax)[512]) {
  constexpr int C2 = C / 2;
  constexpr int P2 = C2 / 2;
  constexpr int CH = P2 / 64;
  const int w = threadIdx.x >> 6;
  const int lane = threadIdx.x & 63;
  const int* sg = segs + ((size_t)b * 64 + t) * 4;
  const ushort* Xb = Xt + (size_t)b * L * C;
#pragma unroll
  for (int h = 0; h < 2; h++) {
    const int s = min(max(sg[2 * h], 0), L - 1);
    const int e = max(min(max(sg[2 * h + 1], 0), L - 1), s);
#pragma unroll
    for (int q = 0; q < CH; q++) {
      const int p = q * 64 + lane;
      const ushort* base = Xb + h * C2 + 2 * p;
      float a0 = -INFINITY, a1 = -INFINITY;
      float c0 = -INFINITY, c1 = -INFINITY;
      int l = s + w;
      for (; l + 4 <= e; l += 8) {
        const unsigned u0 = *(const unsigned*)(base + (size_t)l * C);
        const unsigned u1 = *(const unsigned*)(base + (size_t)(l + 4) * C);
        a0 = fmaxf(a0, bf2f(u0 & 0xffffu));
        a1 = fmaxf(a1, bf2f(u0 >> 16));
        c0 = fmaxf(c0, bf2f(u1 & 0xffffu));
        c1 = fmaxf(c1, bf2f(u1 >> 16));
      }
      if (l <= e) {
        const unsigned u0 = *(const unsigned*)(base + (size_t)l * C);
        a0 = fmaxf(a0, bf2f(u0 & 0xffffu));
        a1 = fmaxf(a1, bf2f(u0 >> 16));
      }
      pmax[w][h * P2 + p] = make_float2(fmaxf(a0, c0), fmaxf(a1, c1));
    }
  }
  __syncthreads();
  for (int idx = threadIdx.x; idx < 2 * P2; idx += 256) {
    float2 m = pmax[0][idx];
#pragma unroll
    for (int ww = 1; ww < 4; ww++) {
      const float2 v = pmax[ww][idx];
      m.x = fmaxf(m.x, v.x);
      m.y = fmaxf(m.y, v.y);
    }
    const unsigned o = (unsigned)f2bf(m.x) | ((unsigned)f2bf(m.y) << 16);
    *(unsigned*)(Y + ((size_t)(b * 64) + t) * rowStride + chOff + 2 * idx) = o;
  }
}

// ---------------------------------------------------------------------------
// ORIGINAL (round-0) anchor-conv MFMA body: waves split taps, split-K+split-C
// slices, fused gather, 4-round LDS accumulate, P [slice][b][o(512)][t(64)].
// ---------------------------------------------------------------------------
template <int Kf, int L, int Cin>
__device__ void anchor_mfma_body(const ushort* __restrict__ src,
                                 const int* __restrict__ anc,
                                 const ushort* __restrict__ Wt,
                                 float* __restrict__ P, int nt, int b,
                                 int slice, float* red) {
  const int w = threadIdx.x >> 6;
  const int lane = threadIdx.x & 63;
  const int l15 = lane & 15, l4 = lane >> 4;
  const int kz = slice >> 1, chalf = slice & 1;
  const int k = kz * 4 + w;
  const int cbase = chalf * (Cin / 2);

  const ushort* rp[4];
#pragma unroll
  for (int i = 0; i < 4; i++) {
    const int t = i * 16 + l15;
    const int a0 = anc[((size_t)b * 64 + t) * 2 + 0];
    const int a1 = anc[((size_t)b * 64 + t) * 2 + 1];
    const int left = min(max(a0, 0), L);
    const int right = min(max(a1, 0), L);
    const int seglen = right + 1 - left;
    const int ix = min(max(left + (k * seglen) / Kf, 0), L - 1);
    rp[i] = src + ((size_t)b * L + ix) * Cin + cbase + l4 * 8;
  }
  const ushort* wb = Wt + (size_t)(nt * Kf + k) * (Cin >> 5) * 2048 + lane * 8;

  f32x4 acc[4][4] = {};
  for (int c0 = 0; c0 < Cin / 2; c0 += 32) {
    const int cc = (cbase + c0) >> 5;
    short8 a[4], bb[4];
#pragma unroll
    for (int i = 0; i < 4; i++) a[i] = *(const short8*)(rp[i] + c0);
#pragma unroll
    for (int j = 0; j < 4; j++)
      bb[j] = *(const short8*)(wb + ((size_t)cc * 4 + j) * 512);
#pragma unroll
    for (int i = 0; i < 4; i++)
#pragma unroll
      for (int j = 0; j < 4; j++)
        acc[i][j] = __builtin_amdgcn_mfma_f32_16x16x32_bf16(a[i], bb[j],
                                                            acc[i][j], 0, 0, 0);
  }

  for (int ww = 0; ww < 4; ww++) {
    __syncthreads();
    if (w == ww) {
#pragma unroll
      for (int i = 0; i < 4; i++)
#pragma unroll
        for (int j = 0; j < 4; j++)
#pragma unroll
          for (int r = 0; r < 4; r++) {
            const int m = i * 16 + l4 * 4 + r;
            const int n = j * 16 + l15;
            if (ww == 0)
              red[m * 65 + n] = acc[i][j][r];
            else
              red[m * 65 + n] += acc[i][j][r];
          }
    }
  }
  __syncthreads();
  float* Pp = P + (((size_t)slice * BB + b) * 512 + nt * 64) * 64;
  for (int e = threadIdx.x; e < 4096; e += 256) {
    const int n = e >> 6, m = e & 63;
    Pp[e] = red[m * 65 + n];
  }
}

// ---------------------------------------------------------------------------
// Anchor split-K reduce + valid mask + bias -> bf16 transposed rows.
// Reads P layout [slice][b][o][t] (round-0).
// ---------------------------------------------------------------------------
__device__ void anchor_reduce_body(const float* __restrict__ P, int ks,
                                   const float* __restrict__ bias,
                                   const int* __restrict__ anc, int L,
                                   ushort* __restrict__ Y, int rowStride,
                                   int chOff, int ot, int b, float* smem) {
  float* tile = smem;
  float* sval = smem + 4160;
  const int o0 = ot * 64;
  if (threadIdx.x < 64) {
    const int t = threadIdx.x;
    const int a0 = anc[((size_t)b * 64 + t) * 2 + 0];
    const int a1 = anc[((size_t)b * 64 + t) * 2 + 1];
    const int left = min(max(a0, 0), L);
    const int right = min(max(a1, 0), L);
    sval[t] = (right > left) ? 1.f : 0.f;
  }
  __syncthreads();
  for (int e = threadIdx.x; e < 4096; e += 256) {
    const int nl = e >> 6, m = e & 63;
    const int n = o0 + nl;
    float s = 0.f;
    for (int z = 0; z < ks; z++)
      s += P[(((size_t)z * BB + b) * 512 + n) * 64 + m];
    tile[nl * 65 + m] = s * sval[m] + bias[n];
  }
  __syncthreads();
  for (int e = threadIdx.x; e < 4096; e += 256) {
    const int m = e >> 6, nl = e & 63;
    Y[((size_t)(b * 64) + m) * rowStride + chOff + o0 + nl] =
        f2bf(tile[nl * 65 + m]);
  }
}

// ---------------------------------------------------------------------------
// Fused launch B (needs only prep outputs):
//   [0,256)   frame anchor-conv, 4 slices (round-0 body)  -> P0
//   [256,448) fm_short + feat_lr GEMM+GN -> cat[1536:2048], feat_lr, FlrT
//   [448,960) frame BMP                  -> XbmpT
// ---------------------------------------------------------------------------
__global__ __launch_bounds__(256) void fused_B_kernel(
    const ushort* __restrict__ Ft, const ushort* __restrict__ Wcomb,
    const float* __restrict__ b_cur, const float* __restrict__ g_cur,
    const float* __restrict__ be_cur, ushort* __restrict__ cat,
    const float* __restrict__ b_lr, const float* __restrict__ g_lr,
    const float* __restrict__ be_lr, float* __restrict__ feat_lr,
    ushort* __restrict__ FlrT, const ushort* __restrict__ FfT,
    const int* __restrict__ frame_segs, ushort* __restrict__ XbmpT,
    const int* __restrict__ frame_anchor, const ushort* __restrict__ Wcp0T,
    float* __restrict__ P0) {
  __shared__ __align__(16) float smem[4240];
  const int bid = blockIdx.x;
  if (bid < 256) {
    const int nt = bid & 7, b = (bid >> 3) & 7, s = bid >> 6;  // s in [0,4)
    anchor_mfma_body<8, 256, 512>(FfT, frame_anchor, Wcp0T, P0, nt, b, s, smem);
  } else if (bid < 448) {
    const int r = bid - 256;
    const int b = r / 24, ot24 = r % 24;
    if (ot24 < 8)
      gemm_gn_body(Ft, Wcomb, b_cur, g_cur, be_cur, 512, 4, nullptr, 0, cat,
                   CATP, 1536, ot24, b, smem);
    else
      gemm_gn_body(Ft, Wcomb + 512 * 512, b_lr, g_lr, be_lr, 512, 5, feat_lr,
                   1024, FlrT, 1024, 0, ot24 - 8, b, smem);
  } else {
    const int r = bid - 448;
    bmp_body<512, 256>(FfT, frame_segs, XbmpT, 512, 0, r & 63, r >> 6,
                       (float2(*)[512])smem);
  }
}

// ---------------------------------------------------------------------------
// Fused launch C (needs B outputs):
//   [0,512)    con anchor-conv, 8 slices (round-0 body)  -> P1
//   [512,576)  prop_roi GEMM+GN         -> cat[0:512]
//   [576,640)  frame reduce (ks=4)      -> FconT
//   [640,1152) con BMP                  -> cat[512:1536]
// ---------------------------------------------------------------------------
__global__ __launch_bounds__(256) void fused_C_kernel(
    const ushort* __restrict__ FlrT, const int* __restrict__ segments,
    ushort* __restrict__ cat, const int* __restrict__ anchor,
    const ushort* __restrict__ WcpT, float* __restrict__ P1,
    const float* __restrict__ P0, const float* __restrict__ b_cp0,
    const int* __restrict__ frame_anchor, ushort* __restrict__ FconT,
    const ushort* __restrict__ XbmpT, const ushort* __restrict__ Wroi,
    const float* __restrict__ b_roi, const float* __restrict__ g_roi,
    const float* __restrict__ be_roi) {
  __shared__ __align__(16) float smem[4240];
  const int bid = blockIdx.x;
  if (bid < 512) {
    const int nt = bid & 7, b = (bid >> 3) & 7, s = bid >> 6;  // s in [0,8)
    anchor_mfma_body<16, 64, 1024>(FlrT, anchor, WcpT, P1, nt, b, s, smem);
  } else if (bid < 576) {
    const int r = bid - 512;
    gemm_gn_body(XbmpT, Wroi, b_roi, g_roi, be_roi, 512, 4, nullptr, 0, cat,
                 CATP, 0, r & 7, r >> 3, smem);
  } else if (bid < 640) {
    const int r = bid - 576;
    anchor_reduce_body(P0, 4, b_cp0, frame_anchor, 256, FconT, 512, 0, r & 7,
                       r >> 3, smem);
  } else {
    const int r = bid - 640;
    bmp_body<1024, 64>(FlrT, segments, cat, CATP, 512, r & 63, r >> 6,
                       (float2(*)[512])smem);
  }
}

// ---------------------------------------------------------------------------
// Fused launch D (needs C outputs):
//   [0,192)   final-proj partials over ready cat cols kc<79 (K<2528), 3 slices
//   [192,256) con reduce (ks=8)  -> cat[2546:3058]
//   [256,320) prop_con GEMM+GN   -> cat[3058:3570]
// (partials read only K<2528 <= 2546: all those cat cols written in A/B/C)
// ---------------------------------------------------------------------------
__global__ __launch_bounds__(256) void fused_D_kernel(
    const ushort* __restrict__ cat, const ushort* __restrict__ Wprop,
    float* __restrict__ P9, const float* __restrict__ P1,
    const float* __restrict__ b_cp, const int* __restrict__ anchor,
    ushort* __restrict__ catw, const ushort* __restrict__ FconT,
    const ushort* __restrict__ Wroi, const float* __restrict__ b_roi,
    const float* __restrict__ g_roi, const float* __restrict__ be_roi) {
  __shared__ __align__(16) float smem[4240];
  const int bid = blockIdx.x;
  if (bid < 192) {
    const int s = bid >> 6, q = bid & 63;
    const int kc0 = (s == 0) ? 0 : (s == 1) ? 27 : 53;
    const int kc1 = (s == 0) ? 27 : (s == 1) ? 53 : 79;
    gemm_part_body(cat, Wprop, P9, q & 7, q >> 3, s, kc0, kc1, smem);
  } else if (bid < 256) {
    const int r = bid - 192;
    anchor_reduce_body(P1, 8, b_cp, anchor, 64, catw, CATP, 2546, r & 7,
                       r >> 3, smem);
  } else {
    const int r = bid - 256;
    gemm_gn_body(FconT, Wroi, b_roi, g_roi, be_roi, 512, 4, nullptr, 0, catw,
                 CATP, 3058, r & 7, r >> 3, smem);
  }
}

extern "C" void kernel_launch(void* const* d_in, const int* in_sizes, int n_in,
                              void* d_out, int out_size, void* d_ws,
                              size_t ws_size, hipStream_t stream) {
  const float* feature      = (const float*)d_in[0];
  const float* frame_feat   = (const float*)d_in[1];
  const int*   segments     = (const int*)d_in[2];
  const int*   frame_segs   = (const int*)d_in[3];
  const float* feat_lastcls = (const float*)d_in[4];
  const int*   anchor       = (const int*)d_in[5];
  const int*   frame_anchor = (const int*)d_in[6];
  const float* locres       = (const float*)d_in[8];
  const float* w_cur  = (const float*)d_in[9];
  const float* b_cur  = (const float*)d_in[10];
  const float* g_cur  = (const float*)d_in[11];
  const float* be_cur = (const float*)d_in[12];
  const float* w_lr   = (const float*)d_in[13];
  const float* b_lr   = (const float*)d_in[14];
  const float* g_lr   = (const float*)d_in[15];
  const float* be_lr  = (const float*)d_in[16];
  const float* w_roi  = (const float*)d_in[17];
  const float* b_roi  = (const float*)d_in[18];
  const float* g_roi  = (const float*)d_in[19];
  const float* be_roi = (const float*)d_in[20];
  const float* w_cp   = (const float*)d_in[21];  // [512,1024,16]
  const float* b_cp   = (const float*)d_in[22];
  const float* w_cp0  = (const float*)d_in[23];  // [512,512,8]
  const float* b_cp0  = (const float*)d_in[24];
  const float* w_prop = (const float*)d_in[25];  // [512,3572]
  const float* b_prop = (const float*)d_in[26];
  const float* g_prop = (const float*)d_in[27];
  const float* be_prop= (const float*)d_in[28];

  float* out_main = (float*)d_out;                  // [8,512,64]
  float* feat_lr  = (float*)d_out + BB * 512 * 64;  // [8,1024,64]

  // workspace layout (ushort units) — round-0 sizes
  ushort* cat_t  = (ushort*)d_ws;             // 1,835,008
  ushort* Ft     = cat_t + 1835008;           // 262,144
  ushort* XbmpT  = Ft + 262144;               // 262,144
  ushort* FconT  = XbmpT + 262144;            // 262,144
  ushort* Wcomb  = FconT + 262144;            // 786,432 (frag)
  ushort* Wroi   = Wcomb + 786432;            // 262,144 (frag)
  ushort* Wprop  = Wroi + 262144;             // 1,835,008 (frag)
  ushort* WcpT   = Wprop + 1835008;           // 8,388,608 (frag)
  ushort* Wcp0T  = WcpT + 8388608;            // 2,097,152 (frag)
  ushort* FlrT   = Wcp0T + 2097152;           // 524,288  [8*64][1024]
  ushort* FfT    = FlrT + 524288;             // 1,048,576 [8*256][512]
  float*  P1     = (float*)(FfT + 1048576);   // 2,097,152 f (8 slices [s][b][o][t])
  float*  P0     = P1 + 2097152;              // 1,048,576 f (4 slices [s][b][o][t])
  float*  P9     = P0 + 1048576;              // 786,432 f (3 slices [s][b][o][t])
  // total ~52 MB

  // A: all weight converts + activation transposes (round-0 prep)
  prep_kernel<<<2184, 256, 0, stream>>>(
      w_cur, w_lr, w_roi, w_prop, Wcomb, Wroi, Wprop, w_cp, WcpT, w_cp0,
      Wcp0T, feature, frame_feat, feat_lastcls, locres, Ft, FfT, cat_t);

  // B: frame anchor-conv | fm_short+feat_lr GEMM+GN | frame BMP
  fused_B_kernel<<<960, 256, 0, stream>>>(
      Ft, Wcomb, b_cur, g_cur, be_cur, cat_t, b_lr, g_lr, be_lr, feat_lr,
      FlrT, FfT, frame_segs, XbmpT, frame_anchor, Wcp0T, P0);

  // C: con anchor-conv | prop_roi | frame reduce -> FconT | con BMP
  fused_C_kernel<<<1152, 256, 0, stream>>>(
      FlrT, segments, cat_t, anchor, WcpT, P1, P0, b_cp0, frame_anchor, FconT,
      XbmpT, Wroi, b_roi, g_roi, be_roi);

  // D: final-proj partials K<2528 | con reduce -> cat | prop_con -> cat
  fused_D_kernel<<<320, 256, 0, stream>>>(
      cat_t, Wprop, P9, P1, b_cp, anchor, cat_t, FconT, Wroi, b_roi, g_roi,
      be_roi);

  // F: last-K GEMM + 3-slice reduce + bias + GN + ReLU -> out_main
  reduce_gn_kernel<<<dim3(8, BB), 256, 0, stream>>>(
      cat_t, Wprop, P9, b_prop, g_prop, be_prop, out_main);
}